// Round 7
// baseline (354.242 us; speedup 1.0000x reference)
//
#include <hip/hip_runtime.h>
#include <hip/hip_bf16.h>

typedef __attribute__((ext_vector_type(8))) short bf16x8_t;
typedef __attribute__((ext_vector_type(16))) float f32x16_t;
typedef unsigned short u16;
typedef unsigned int u32;

__device__ __forceinline__ u16 f2bf(float f) {
  union { float f; u32 u; } v; v.f = f;
  u32 u = v.u;
  return (u16)((u + 0x7fffu + ((u >> 16) & 1u)) >> 16);
}

// ---------------- setup kernel A: kvp GEMM (blocks 0..351) + Wq cast (352..479)
__global__ void k_setupA(const float* __restrict__ kv, const float* __restrict__ Wkv,
                         const float* __restrict__ Wq,
                         float* __restrict__ kvp, u16* __restrict__ Wq_bf) {
  __shared__ float kvL[7 * 768];
  const int bx = blockIdx.x;
  const int tid = threadIdx.x;
  if (bx < 352) {
    const int jc = bx & 15, lt = (bx >> 4) % 11, b = bx / 176;
    const float* kvb = kv + ((size_t)b * 77 + (size_t)lt * 7) * 768;
    for (int i = tid; i < 7 * 768 / 4; i += 256)
      reinterpret_cast<float4*>(kvL)[i] = reinterpret_cast<const float4*>(kvb)[i];
    __syncthreads();
    const int j = jc * 64 + (tid & 63);
    const int lgc = tid >> 6;
    const bool has1 = (lgc < 3);
    float a0 = 0.f, a1 = 0.f;
    const float4* Wr = reinterpret_cast<const float4*>(Wkv + (size_t)j * 768);
    const float4* k0 = reinterpret_cast<const float4*>(kvL + lgc * 768);
    const float4* k1 = reinterpret_cast<const float4*>(kvL + (lgc + 4) * 768);
    #pragma unroll 4
    for (int k4 = 0; k4 < 192; ++k4) {
      float4 wv = Wr[k4];
      float4 x0 = k0[k4];
      a0 += wv.x * x0.x + wv.y * x0.y + wv.z * x0.z + wv.w * x0.w;
      if (has1) {
        float4 x1 = k1[k4];
        a1 += wv.x * x1.x + wv.y * x1.y + wv.z * x1.z + wv.w * x1.w;
      }
    }
    const int lbase = b * 77 + lt * 7;
    kvp[(size_t)(lbase + lgc) * 1024 + j] = a0;
    if (has1) kvp[(size_t)(lbase + lgc + 4) * 1024 + j] = a1;
  } else {
    int i = (bx - 352) * 256 + tid;
    float4 v = reinterpret_cast<const float4*>(Wq)[i];
    uint2 p;
    p.x = (u32)f2bf(v.x) | ((u32)f2bf(v.y) << 16);
    p.y = (u32)f2bf(v.z) | ((u32)f2bf(v.w) << 16);
    reinterpret_cast<uint2*>(Wq_bf)[i] = p;
  }
}

// ---------------- setup kernel B: k-softmax + context + M, fused. grid (8,2), 256 thr
__global__ void k_setupB(const float* __restrict__ kvp, const float* __restrict__ Wout,
                         u16* __restrict__ M_bf) {
  extern __shared__ float sm[];
  float* ks   = sm;           // 77*64 = 4928
  float* vs   = sm + 4928;    // 4928
  float* red  = sm + 9856;    // 256
  float* mcol = sm + 10112;   // 64
  float* icol = sm + 10176;   // 64
  float* ctxl = sm + 10240;   // [e][d] 4096
  float* Wt   = sm + 14336;   // [e][257] padded, 16448  -> total 30784 f = 123136 B
  const int h = blockIdx.x, b = blockIdx.y;
  const int tid = threadIdx.x;
  const float* base = kvp + (size_t)b * 77 * 1024;
  for (int i = tid; i < 77 * 64; i += 256) {
    int ll = i >> 6, d = i & 63;
    ks[i] = base[(size_t)ll * 1024 + h * 64 + d];
    vs[i] = base[(size_t)ll * 1024 + 512 + h * 64 + d];
  }
  for (int i = tid; i < 16384; i += 256) {
    int o = i >> 6, e = i & 63;
    Wt[e * 257 + o] = Wout[(size_t)o * 512 + h * 64 + e];
  }
  __syncthreads();
  const int d = tid & 63, part = tid >> 6;
  float m = -1e30f;
  for (int ll = part; ll < 77; ll += 4) m = fmaxf(m, ks[ll * 64 + d]);
  red[part * 64 + d] = m;
  __syncthreads();
  float mfull = fmaxf(fmaxf(red[d], red[64 + d]), fmaxf(red[128 + d], red[192 + d]));
  float s = 0.f;
  for (int ll = part; ll < 77; ll += 4) s += __expf(ks[ll * 64 + d] - mfull);
  __syncthreads();
  red[part * 64 + d] = s;
  __syncthreads();
  if (part == 0) {
    float S = red[d] + red[64 + d] + red[128 + d] + red[192 + d];
    mcol[d] = mfull;
    icol[d] = 1.0f / S;
  }
  __syncthreads();
  for (int i = tid; i < 77 * 64; i += 256) {
    int dd = i & 63;
    ks[i] = __expf(ks[i] - mcol[dd]) * icol[dd];
  }
  __syncthreads();
  const int dg = tid & 15, eg = tid >> 4;
  float acc[4][4];
  #pragma unroll
  for (int a = 0; a < 4; ++a)
    #pragma unroll
    for (int c = 0; c < 4; ++c) acc[a][c] = 0.f;
  for (int ll = 0; ll < 77; ++ll) {
    float4 kk = *reinterpret_cast<const float4*>(ks + ll * 64 + dg * 4);
    float4 vv = *reinterpret_cast<const float4*>(vs + ll * 64 + eg * 4);
    float kd[4] = {kk.x, kk.y, kk.z, kk.w};
    float ve[4] = {vv.x, vv.y, vv.z, vv.w};
    #pragma unroll
    for (int di = 0; di < 4; ++di)
      #pragma unroll
      for (int ei = 0; ei < 4; ++ei) acc[di][ei] += kd[di] * ve[ei];
  }
  #pragma unroll
  for (int ei = 0; ei < 4; ++ei) {
    float4 row;
    row.x = acc[0][ei]; row.y = acc[1][ei]; row.z = acc[2][ei]; row.w = acc[3][ei];
    *reinterpret_cast<float4*>(ctxl + (size_t)(eg * 4 + ei) * 64 + dg * 4) = row;
  }
  __syncthreads();
  const int og = tid & 15, dgm = tid >> 4;
  float am[16][4];
  #pragma unroll
  for (int a = 0; a < 16; ++a)
    #pragma unroll
    for (int c = 0; c < 4; ++c) am[a][c] = 0.f;
  for (int e = 0; e < 64; ++e) {
    float4 cv = *reinterpret_cast<const float4*>(ctxl + e * 64 + dgm * 4);
    float cd[4] = {cv.x, cv.y, cv.z, cv.w};
    const float* wrow = Wt + e * 257 + og * 16;
    #pragma unroll
    for (int oi = 0; oi < 16; ++oi) {
      float wo = wrow[oi];
      #pragma unroll
      for (int di = 0; di < 4; ++di) am[oi][di] += wo * cd[di];
    }
  }
  #pragma unroll
  for (int oi = 0; oi < 16; ++oi) {
    int o = og * 16 + oi;
    uint2 p;
    p.x = (u32)f2bf(am[oi][0]) | ((u32)f2bf(am[oi][1]) << 16);
    p.y = (u32)f2bf(am[oi][2]) | ((u32)f2bf(am[oi][3]) << 16);
    *reinterpret_cast<uint2*>(M_bf + ((size_t)((b * 8 + h) * 256 + o)) * 64 + dgm * 4) = p;
  }
}

// ---------------- fused main kernel: BN=128, 4 waves, zero inner barriers.
// Each wave owns 32 pixels end-to-end; P redistributed in-register via
// cvt_pk_bf16 + permlane32_swap (no QT LDS, no sync). grid 1024.
__global__ __launch_bounds__(256, 2) void k_main(
    const float* __restrict__ x, const u16* __restrict__ Wq_bf,
    const u16* __restrict__ M_bf, const float* __restrict__ bout,
    float* __restrict__ out) {
  extern __shared__ char smem[];
  u16* Xl = reinterpret_cast<u16*>(smem);            // [128 n][256 c] bf16 swz, 64 KB

  const int tid = threadIdx.x;
  const int w = tid >> 6, l = tid & 63;
  const int l31 = l & 31, hi = l >> 5;

  const int bi = blockIdx.x;
  const int b = bi >> 9;              // 512 tiles per batch
  const int n0 = (bi & 511) * 128;
  const float* xb = x + (size_t)b * 16777216 + n0;

  // ---- stage X tile: fp32 [c][n] -> bf16 LDS [n][c] swizzled
  {
    const int n = tid & 127;
    const int ch = tid >> 7;          // c-half 0/1
    #pragma unroll 4
    for (int it = 0; it < 32; ++it) {
      const int c0 = ch * 128 + it * 4;
      float f0 = xb[(size_t)(c0 + 0) * 65536 + n];
      float f1 = xb[(size_t)(c0 + 1) * 65536 + n];
      float f2 = xb[(size_t)(c0 + 2) * 65536 + n];
      float f3 = xb[(size_t)(c0 + 3) * 65536 + n];
      uint2 p;
      p.x = (u32)f2bf(f0) | ((u32)f2bf(f1) << 16);
      p.y = (u32)f2bf(f2) | ((u32)f2bf(f3) << 16);
      u32 boff = (u32)n * 512u + (((u32)(c0 * 2)) ^ (((u32)n & 7u) << 4));
      *reinterpret_cast<uint2*>(reinterpret_cast<char*>(Xl) + boff) = p;
    }
  }

  f32x16_t acc[8];                    // GEMM2 acc: 256 o x 32 n per wave, 128 VGPR
  #pragma unroll
  for (int i = 0; i < 8; ++i) acc[i] = (f32x16_t)(0.0f);

  __syncthreads();                    // the ONLY block barrier

  const int myn = w * 32 + l31;       // this wave's pixel column
  const u32 bswz = ((u32)l31 & 7u) << 4;

  for (int h = 0; h < 8; ++h) {
    // ---- GEMM1: S[64 d][32 n] for own pixels, swapped layout (d in regs).
    f32x16_t s0 = (f32x16_t)(0.0f), s1 = (f32x16_t)(0.0f);
    {
      const u16* wq0 = Wq_bf + (size_t)h * 16384 + (size_t)l31 * 256 + hi * 8;
      #pragma unroll 8
      for (int ks = 0; ks < 16; ++ks) {
        bf16x8_t bx = *reinterpret_cast<const bf16x8_t*>(reinterpret_cast<const char*>(Xl) +
                       (u32)myn * 512u + (((u32)(ks * 32 + hi * 16)) ^ bswz));
        bf16x8_t a0 = *reinterpret_cast<const bf16x8_t*>(wq0 + ks * 16);
        bf16x8_t a1 = *reinterpret_cast<const bf16x8_t*>(wq0 + 8192 + ks * 16);
        s0 = __builtin_amdgcn_mfma_f32_32x32x16_bf16(a0, bx, s0, 0, 0, 0);
        s1 = __builtin_amdgcn_mfma_f32_32x32x16_bf16(a1, bx, s1, 0, 0, 0);
      }
    }

    // ---- lane-local softmax over d (lane holds 32 of 64 d's; partner ^32 rest)
    float mx = s0[0];
    #pragma unroll
    for (int r = 1; r < 16; ++r) mx = fmaxf(mx, s0[r]);
    #pragma unroll
    for (int r = 0; r < 16; ++r) mx = fmaxf(mx, s1[r]);
    mx = fmaxf(mx, __shfl_xor(mx, 32, 64));
    float sum = 0.f;
    #pragma unroll
    for (int r = 0; r < 16; ++r) { float e = __expf(s0[r] - mx); s0[r] = e; sum += e; }
    #pragma unroll
    for (int r = 0; r < 16; ++r) { float e = __expf(s1[r] - mx); s1[r] = e; sum += e; }
    sum += __shfl_xor(sum, 32, 64);
    const float sc = 0.125f / sum;
    #pragma unroll
    for (int r = 0; r < 16; ++r) { s0[r] *= sc; s1[r] *= sc; }

    // ---- GEMM2: Out[256 o][32 n] += M_h @ P. B built in-register:
    // d bits: d[1:0]=reg[1:0], d[2]=src half, d[3]=tgt half (reg[2]), d[4]=ks&1
    // (reg[3]), d[5]=s0/s1. Per ks: 4 cvt_pk + 2 permlane32_swap.
    const u16* msrc = M_bf + ((size_t)(b * 8 + h) * 256 + l31) * 64 + hi * 8;
    #define GEMM2_KS(KS, SV)                                                          \
    {                                                                                 \
      u32 A_, B_, C_, D_;                                                             \
      asm("v_cvt_pk_bf16_f32 %0, %1, %2" : "=v"(A_)                                   \
          : "v"(SV[((KS & 1) * 8) + 0]), "v"(SV[((KS & 1) * 8) + 1]));                \
      asm("v_cvt_pk_bf16_f32 %0, %1, %2" : "=v"(B_)                                   \
          : "v"(SV[((KS & 1) * 8) + 2]), "v"(SV[((KS & 1) * 8) + 3]));                \
      asm("v_cvt_pk_bf16_f32 %0, %1, %2" : "=v"(C_)                                   \
          : "v"(SV[((KS & 1) * 8) + 4]), "v"(SV[((KS & 1) * 8) + 5]));                \
      asm("v_cvt_pk_bf16_f32 %0, %1, %2" : "=v"(D_)                                   \
          : "v"(SV[((KS & 1) * 8) + 6]), "v"(SV[((KS & 1) * 8) + 7]));                \
      asm("v_permlane32_swap_b32 %0, %1" : "+v"(A_), "+v"(C_));                       \
      asm("v_permlane32_swap_b32 %0, %1" : "+v"(B_), "+v"(D_));                       \
      union { uint4 u; bf16x8_t v; } fr_;                                             \
      fr_.u.x = A_; fr_.u.y = B_; fr_.u.z = C_; fr_.u.w = D_;                         \
      _Pragma("unroll")                                                               \
      for (int ot = 0; ot < 8; ++ot) {                                                \
        bf16x8_t a = *reinterpret_cast<const bf16x8_t*>(msrc + ot * 2048 + KS * 16);  \
        acc[ot] = __builtin_amdgcn_mfma_f32_32x32x16_bf16(a, fr_.v, acc[ot], 0, 0, 0);\
      }                                                                               \
    }
    GEMM2_KS(0, s0)
    GEMM2_KS(1, s0)
    GEMM2_KS(2, s1)
    GEMM2_KS(3, s1)
    #undef GEMM2_KS
  }

  // ---- epilogue: bias + store fp32
  #pragma unroll
  for (int ot = 0; ot < 8; ++ot) {
    #pragma unroll
    for (int r = 0; r < 16; ++r) {
      const int o = ot * 32 + (r & 3) + 8 * (r >> 2) + 4 * hi;
      out[((size_t)b * 256 + o) * 65536 + n0 + w * 32 + l31] = acc[ot][r] + bout[o];
    }
  }
}

extern "C" void kernel_launch(void* const* d_in, const int* in_sizes, int n_in,
                              void* d_out, int out_size, void* d_ws, size_t ws_size,
                              hipStream_t stream) {
  (void)in_sizes; (void)n_in; (void)out_size; (void)ws_size;
  const float* x    = (const float*)d_in[0];
  const float* kv   = (const float*)d_in[1];
  const float* Wq   = (const float*)d_in[2];
  const float* Wkv  = (const float*)d_in[3];
  const float* Wout = (const float*)d_in[4];
  const float* bout = (const float*)d_in[5];
  float* out = (float*)d_out;

  char* ws = (char*)d_ws;
  float* kvp   = (float*)(ws);                       // 2*77*1024*4   = 630784 B
  u16*   M_bf  = (u16*)(ws + 630784);                // 2*8*256*64*2  = 524288 B
  u16*   Wq_bf = (u16*)(ws + 630784 + 524288);       // 512*256*2     = 262144 B

  hipFuncSetAttribute(reinterpret_cast<const void*>(k_setupB),
                      hipFuncAttributeMaxDynamicSharedMemorySize, 123136);
  hipFuncSetAttribute(reinterpret_cast<const void*>(k_main),
                      hipFuncAttributeMaxDynamicSharedMemorySize, 65536);

  k_setupA<<<480, 256, 0, stream>>>(kv, Wkv, Wq, kvp, Wq_bf);
  k_setupB<<<dim3(8, 2), 256, 123136, stream>>>(kvp, Wout, M_bf);
  k_main<<<1024, 256, 65536, stream>>>(x, Wq_bf, M_bf, bout, out);
}

// Round 8
// 245.042 us; speedup vs baseline: 1.4456x; 1.4456x over previous
//
#include <hip/hip_runtime.h>
#include <hip/hip_bf16.h>

typedef __attribute__((ext_vector_type(8))) short bf16x8_t;
typedef __attribute__((ext_vector_type(16))) float f32x16_t;
typedef unsigned short u16;
typedef unsigned int u32;

__device__ __forceinline__ u16 f2bf(float f) {
  union { float f; u32 u; } v; v.f = f;
  u32 u = v.u;
  return (u16)((u + 0x7fffu + ((u >> 16) & 1u)) >> 16);
}

// ---------------- setup kernel A: kvp GEMM (blocks 0..351) + Wq fragment-cast (352..415)
// Wq_fr[h][t][ks][l(64)][j(8)] = bf16(Wq[h*64 + t*32 + (l&31)][ks*16 + (l>>5)*8 + j])
__global__ void k_setupA(const float* __restrict__ kv, const float* __restrict__ Wkv,
                         const float* __restrict__ Wq,
                         float* __restrict__ kvp, u16* __restrict__ Wq_fr) {
  __shared__ float kvL[7 * 768];
  const int bx = blockIdx.x;
  const int tid = threadIdx.x;
  if (bx < 352) {
    const int jc = bx & 15, lt = (bx >> 4) % 11, b = bx / 176;
    const float* kvb = kv + ((size_t)b * 77 + (size_t)lt * 7) * 768;
    for (int i = tid; i < 7 * 768 / 4; i += 256)
      reinterpret_cast<float4*>(kvL)[i] = reinterpret_cast<const float4*>(kvb)[i];
    __syncthreads();
    const int j = jc * 64 + (tid & 63);
    const int lgc = tid >> 6;
    const bool has1 = (lgc < 3);
    float a0 = 0.f, a1 = 0.f;
    const float4* Wr = reinterpret_cast<const float4*>(Wkv + (size_t)j * 768);
    const float4* k0 = reinterpret_cast<const float4*>(kvL + lgc * 768);
    const float4* k1 = reinterpret_cast<const float4*>(kvL + (lgc + 4) * 768);
    #pragma unroll 4
    for (int k4 = 0; k4 < 192; ++k4) {
      float4 wv = Wr[k4];
      float4 x0 = k0[k4];
      a0 += wv.x * x0.x + wv.y * x0.y + wv.z * x0.z + wv.w * x0.w;
      if (has1) {
        float4 x1 = k1[k4];
        a1 += wv.x * x1.x + wv.y * x1.y + wv.z * x1.z + wv.w * x1.w;
      }
    }
    const int lbase = b * 77 + lt * 7;
    kvp[(size_t)(lbase + lgc) * 1024 + j] = a0;
    if (has1) kvp[(size_t)(lbase + lgc + 4) * 1024 + j] = a1;
  } else {
    // one 16B fragment per thread: 16384 fragments total
    const int fid = (bx - 352) * 256 + tid;      // 0..16383
    const int l  = fid & 63;
    const int ks = (fid >> 6) & 15;
    const int t  = (fid >> 10) & 1;
    const int h  = fid >> 11;
    const int row = h * 64 + t * 32 + (l & 31);
    const int col = ks * 16 + (l >> 5) * 8;
    const float4* src = reinterpret_cast<const float4*>(Wq + (size_t)row * 256 + col);
    float4 v0 = src[0], v1 = src[1];
    uint4 o;
    o.x = (u32)f2bf(v0.x) | ((u32)f2bf(v0.y) << 16);
    o.y = (u32)f2bf(v0.z) | ((u32)f2bf(v0.w) << 16);
    o.z = (u32)f2bf(v1.x) | ((u32)f2bf(v1.y) << 16);
    o.w = (u32)f2bf(v1.z) | ((u32)f2bf(v1.w) << 16);
    *reinterpret_cast<uint4*>(Wq_fr + (size_t)fid * 8) = o;
  }
}

// ---------------- setup kernel B: k-softmax + context + M (fragment order). grid (8,2)
// M_fr[b][h][ot(8)][ks(4)][l(64)][j(8)] = bf16(M[ot*32+(l&31)][ks*16+(l>>5)*8+j])
__global__ void k_setupB(const float* __restrict__ kvp, const float* __restrict__ Wout,
                         u16* __restrict__ M_fr) {
  extern __shared__ float sm[];
  float* ks_   = sm;          // 77*64 = 4928
  float* vs   = sm + 4928;    // 4928
  float* red  = sm + 9856;    // 256
  float* mcol = sm + 10112;   // 64
  float* icol = sm + 10176;   // 64
  float* ctxl = sm + 10240;   // [e][d] 4096
  float* Wt   = sm + 14336;   // [e][257] padded, 16448  -> total 30784 f = 123136 B
  const int h = blockIdx.x, b = blockIdx.y;
  const int tid = threadIdx.x;
  const float* base = kvp + (size_t)b * 77 * 1024;
  for (int i = tid; i < 77 * 64; i += 256) {
    int ll = i >> 6, d = i & 63;
    ks_[i] = base[(size_t)ll * 1024 + h * 64 + d];
    vs[i] = base[(size_t)ll * 1024 + 512 + h * 64 + d];
  }
  for (int i = tid; i < 16384; i += 256) {
    int o = i >> 6, e = i & 63;
    Wt[e * 257 + o] = Wout[(size_t)o * 512 + h * 64 + e];
  }
  __syncthreads();
  const int d = tid & 63, part = tid >> 6;
  float m = -1e30f;
  for (int ll = part; ll < 77; ll += 4) m = fmaxf(m, ks_[ll * 64 + d]);
  red[part * 64 + d] = m;
  __syncthreads();
  float mfull = fmaxf(fmaxf(red[d], red[64 + d]), fmaxf(red[128 + d], red[192 + d]));
  float s = 0.f;
  for (int ll = part; ll < 77; ll += 4) s += __expf(ks_[ll * 64 + d] - mfull);
  __syncthreads();
  red[part * 64 + d] = s;
  __syncthreads();
  if (part == 0) {
    float S = red[d] + red[64 + d] + red[128 + d] + red[192 + d];
    mcol[d] = mfull;
    icol[d] = 1.0f / S;
  }
  __syncthreads();
  for (int i = tid; i < 77 * 64; i += 256) {
    int dd = i & 63;
    ks_[i] = __expf(ks_[i] - mcol[dd]) * icol[dd];
  }
  __syncthreads();
  const int dg = tid & 15, eg = tid >> 4;
  float acc[4][4];
  #pragma unroll
  for (int a = 0; a < 4; ++a)
    #pragma unroll
    for (int c = 0; c < 4; ++c) acc[a][c] = 0.f;
  for (int ll = 0; ll < 77; ++ll) {
    float4 kk = *reinterpret_cast<const float4*>(ks_ + ll * 64 + dg * 4);
    float4 vv = *reinterpret_cast<const float4*>(vs + ll * 64 + eg * 4);
    float kd[4] = {kk.x, kk.y, kk.z, kk.w};
    float ve[4] = {vv.x, vv.y, vv.z, vv.w};
    #pragma unroll
    for (int di = 0; di < 4; ++di)
      #pragma unroll
      for (int ei = 0; ei < 4; ++ei) acc[di][ei] += kd[di] * ve[ei];
  }
  #pragma unroll
  for (int ei = 0; ei < 4; ++ei) {
    float4 row;
    row.x = acc[0][ei]; row.y = acc[1][ei]; row.z = acc[2][ei]; row.w = acc[3][ei];
    *reinterpret_cast<float4*>(ctxl + (size_t)(eg * 4 + ei) * 64 + dg * 4) = row;
  }
  __syncthreads();
  const int og = tid & 15, dgm = tid >> 4;
  float am[16][4];
  #pragma unroll
  for (int a = 0; a < 16; ++a)
    #pragma unroll
    for (int c = 0; c < 4; ++c) am[a][c] = 0.f;
  for (int e = 0; e < 64; ++e) {
    float4 cv = *reinterpret_cast<const float4*>(ctxl + e * 64 + dgm * 4);
    float cd[4] = {cv.x, cv.y, cv.z, cv.w};
    const float* wrow = Wt + e * 257 + og * 16;
    #pragma unroll
    for (int oi = 0; oi < 16; ++oi) {
      float wo = wrow[oi];
      #pragma unroll
      for (int di = 0; di < 4; ++di) am[oi][di] += wo * cd[di];
    }
  }
  // write fragment-ordered: d = dgm*4+di -> ks=dgm>>2, hi=(dgm>>1)&1, jo=(dgm&1)*4
  const int ksq = dgm >> 2, hi2 = (dgm >> 1) & 1, jo = (dgm & 1) * 4;
  #pragma unroll
  for (int oi = 0; oi < 16; ++oi) {
    const int o = og * 16 + oi;
    const int ot = o >> 5, lM = hi2 * 32 + (o & 31);
    uint2 p;
    p.x = (u32)f2bf(am[oi][0]) | ((u32)f2bf(am[oi][1]) << 16);
    p.y = (u32)f2bf(am[oi][2]) | ((u32)f2bf(am[oi][3]) << 16);
    *reinterpret_cast<uint2*>(M_fr +
        ((((size_t)(b * 8 + h) * 8 + ot) * 4 + ksq) * 64 + lM) * 8 + jo) = p;
  }
}

// ---------------- fused main kernel: BN=128, 4 waves, zero inner barriers,
// fragment-ordered A loads (1 KB contiguous per instruction). grid 1024.
__global__ __launch_bounds__(256, 2) void k_main(
    const float* __restrict__ x, const u16* __restrict__ Wq_fr,
    const u16* __restrict__ M_fr, const float* __restrict__ bout,
    float* __restrict__ out) {
  extern __shared__ char smem[];
  u16* Xl = reinterpret_cast<u16*>(smem);            // [128 n][256 c] bf16 swz, 64 KB

  const int tid = threadIdx.x;
  const int w = tid >> 6, l = tid & 63;
  const int l31 = l & 31, hi = l >> 5;

  const int bi = blockIdx.x;
  const int b = bi >> 9;              // 512 tiles per batch
  const int n0 = (bi & 511) * 128;
  const float* xb = x + (size_t)b * 16777216 + n0;

  // ---- stage X tile: fp32 [c][n] -> bf16 LDS [n][c] swizzled
  {
    const int n = tid & 127;
    const int ch = tid >> 7;          // c-half 0/1
    #pragma unroll 4
    for (int it = 0; it < 32; ++it) {
      const int c0 = ch * 128 + it * 4;
      float f0 = xb[(size_t)(c0 + 0) * 65536 + n];
      float f1 = xb[(size_t)(c0 + 1) * 65536 + n];
      float f2 = xb[(size_t)(c0 + 2) * 65536 + n];
      float f3 = xb[(size_t)(c0 + 3) * 65536 + n];
      uint2 p;
      p.x = (u32)f2bf(f0) | ((u32)f2bf(f1) << 16);
      p.y = (u32)f2bf(f2) | ((u32)f2bf(f3) << 16);
      u32 boff = (u32)n * 512u + (((u32)(c0 * 2)) ^ (((u32)n & 7u) << 4));
      *reinterpret_cast<uint2*>(reinterpret_cast<char*>(Xl) + boff) = p;
    }
  }

  f32x16_t acc[8];                    // GEMM2 acc: 256 o x 32 n per wave
  #pragma unroll
  for (int i = 0; i < 8; ++i) acc[i] = (f32x16_t)(0.0f);

  __syncthreads();                    // the ONLY block barrier

  const int myn = w * 32 + l31;       // this wave's pixel column
  const u32 bswz = ((u32)l31 & 7u) << 4;

  for (int h = 0; h < 8; ++h) {
    // ---- GEMM1: S[64 d][32 n], swapped layout. A fragment-ordered from global.
    f32x16_t s0 = (f32x16_t)(0.0f), s1 = (f32x16_t)(0.0f);
    {
      const u16* wq0 = Wq_fr + (size_t)h * 16384 + (size_t)l * 8;  // t-stride 8192, ks-stride 512
      #pragma unroll 8
      for (int ks = 0; ks < 16; ++ks) {
        bf16x8_t bx = *reinterpret_cast<const bf16x8_t*>(reinterpret_cast<const char*>(Xl) +
                       (u32)myn * 512u + (((u32)(ks * 32 + hi * 16)) ^ bswz));
        bf16x8_t a0 = *reinterpret_cast<const bf16x8_t*>(wq0 + ks * 512);
        bf16x8_t a1 = *reinterpret_cast<const bf16x8_t*>(wq0 + 8192 + ks * 512);
        s0 = __builtin_amdgcn_mfma_f32_32x32x16_bf16(a0, bx, s0, 0, 0, 0);
        s1 = __builtin_amdgcn_mfma_f32_32x32x16_bf16(a1, bx, s1, 0, 0, 0);
      }
    }

    // ---- lane-local softmax over d (lane holds 32 of 64 d's; partner ^32 rest)
    float mx = s0[0];
    #pragma unroll
    for (int r = 1; r < 16; ++r) mx = fmaxf(mx, s0[r]);
    #pragma unroll
    for (int r = 0; r < 16; ++r) mx = fmaxf(mx, s1[r]);
    mx = fmaxf(mx, __shfl_xor(mx, 32, 64));
    float sum = 0.f;
    #pragma unroll
    for (int r = 0; r < 16; ++r) { float e = __expf(s0[r] - mx); s0[r] = e; sum += e; }
    #pragma unroll
    for (int r = 0; r < 16; ++r) { float e = __expf(s1[r] - mx); s1[r] = e; sum += e; }
    sum += __shfl_xor(sum, 32, 64);
    const float sc = 0.125f / sum;
    #pragma unroll
    for (int r = 0; r < 16; ++r) { s0[r] *= sc; s1[r] *= sc; }

    // ---- GEMM2: Out[256 o][32 n] += M_h @ P. B built in-register (cvt_pk+permlane),
    // A fragment-ordered from global: ot-stride 2048, ks-stride 512.
    const u16* msrc = M_fr + (size_t)(b * 8 + h) * 16384 + (size_t)l * 8;
    #define GEMM2_KS(KS, SV)                                                          \
    {                                                                                 \
      u32 A_, B_, C_, D_;                                                             \
      asm("v_cvt_pk_bf16_f32 %0, %1, %2" : "=v"(A_)                                   \
          : "v"(SV[((KS & 1) * 8) + 0]), "v"(SV[((KS & 1) * 8) + 1]));                \
      asm("v_cvt_pk_bf16_f32 %0, %1, %2" : "=v"(B_)                                   \
          : "v"(SV[((KS & 1) * 8) + 2]), "v"(SV[((KS & 1) * 8) + 3]));                \
      asm("v_cvt_pk_bf16_f32 %0, %1, %2" : "=v"(C_)                                   \
          : "v"(SV[((KS & 1) * 8) + 4]), "v"(SV[((KS & 1) * 8) + 5]));                \
      asm("v_cvt_pk_bf16_f32 %0, %1, %2" : "=v"(D_)                                   \
          : "v"(SV[((KS & 1) * 8) + 6]), "v"(SV[((KS & 1) * 8) + 7]));                \
      asm("v_permlane32_swap_b32 %0, %1" : "+v"(A_), "+v"(C_));                       \
      asm("v_permlane32_swap_b32 %0, %1" : "+v"(B_), "+v"(D_));                       \
      union { uint4 u; bf16x8_t v; } fr_;                                             \
      fr_.u.x = A_; fr_.u.y = B_; fr_.u.z = C_; fr_.u.w = D_;                         \
      _Pragma("unroll")                                                               \
      for (int ot = 0; ot < 8; ++ot) {                                                \
        bf16x8_t a = *reinterpret_cast<const bf16x8_t*>(msrc + ot * 2048 + KS * 512); \
        acc[ot] = __builtin_amdgcn_mfma_f32_32x32x16_bf16(a, fr_.v, acc[ot], 0, 0, 0);\
      }                                                                               \
    }
    GEMM2_KS(0, s0)
    GEMM2_KS(1, s0)
    GEMM2_KS(2, s1)
    GEMM2_KS(3, s1)
    #undef GEMM2_KS
  }

  // ---- epilogue: bias + store fp32
  #pragma unroll
  for (int ot = 0; ot < 8; ++ot) {
    #pragma unroll
    for (int r = 0; r < 16; ++r) {
      const int o = ot * 32 + (r & 3) + 8 * (r >> 2) + 4 * hi;
      out[((size_t)b * 256 + o) * 65536 + n0 + w * 32 + l31] = acc[ot][r] + bout[o];
    }
  }
}

extern "C" void kernel_launch(void* const* d_in, const int* in_sizes, int n_in,
                              void* d_out, int out_size, void* d_ws, size_t ws_size,
                              hipStream_t stream) {
  (void)in_sizes; (void)n_in; (void)out_size; (void)ws_size;
  const float* x    = (const float*)d_in[0];
  const float* kv   = (const float*)d_in[1];
  const float* Wq   = (const float*)d_in[2];
  const float* Wkv  = (const float*)d_in[3];
  const float* Wout = (const float*)d_in[4];
  const float* bout = (const float*)d_in[5];
  float* out = (float*)d_out;

  char* ws = (char*)d_ws;
  float* kvp   = (float*)(ws);                       // 2*77*1024*4   = 630784 B
  u16*   M_fr  = (u16*)(ws + 630784);                // 2*8*8*4*64*8*2 = 524288 B
  u16*   Wq_fr = (u16*)(ws + 630784 + 524288);       // 8*2*16*64*8*2  = 262144 B

  hipFuncSetAttribute(reinterpret_cast<const void*>(k_setupB),
                      hipFuncAttributeMaxDynamicSharedMemorySize, 123136);
  hipFuncSetAttribute(reinterpret_cast<const void*>(k_main),
                      hipFuncAttributeMaxDynamicSharedMemorySize, 65536);

  k_setupA<<<416, 256, 0, stream>>>(kv, Wkv, Wq, kvp, Wq_fr);
  k_setupB<<<dim3(8, 2), 256, 123136, stream>>>(kvp, Wout, M_fr);
  k_main<<<1024, 256, 65536, stream>>>(x, Wq_fr, M_fr, bout, out);
}